// Round 2
// baseline (38.933 us; speedup 1.0000x reference)
//
#include <hip/hip_runtime.h>

typedef __attribute__((ext_vector_type(4))) float f32x4;

#define N_MOLS   2000
#define NATOM    64
#define PPM      (NATOM * (NATOM - 1))   // 4032 pairs per molecule
#define NPAIRS   (N_MOLS * PPM)          // 8,064,000
#define NGROUPS  (NPAIRS / 4)            // 2,016,000 (4032 % 4 == 0 -> groups never cross molecules)

__global__ __launch_bounds__(256) void nl_pairs_kernel(const float* __restrict__ pos,
                                                       float* __restrict__ out) {
    const int g = blockIdx.x * 256 + threadIdx.x;
    if (g >= NGROUPS) return;

    const int k0   = g * 4;              // first pair of this group
    const int mol  = k0 / PPM;
    int       kl   = k0 - mol * PPM;
    const int base = mol * NATOM;
    int i = kl / 63;                     // local i row
    int t = kl - i * 63;                 // slot within row (j skips i)

    const float* mp = pos + (long)base * 3;
    float pix = mp[i*3+0], piy = mp[i*3+1], piz = mp[i*3+2];

    f32x4 vi, vj, vd;
    float rr[12];

    #pragma unroll
    for (int u = 0; u < 4; ++u) {
        const int j = (t < i) ? t : (t + 1);
        const float pjx = mp[j*3+0], pjy = mp[j*3+1], pjz = mp[j*3+2];

        // strict IEEE f32, no FMA contraction -> bit-exact vs numpy:
        // d = sqrt((dx*dx + dy*dy) + dz*dz)
        const float dx = __fsub_rn(pjx, pix);
        const float dy = __fsub_rn(pjy, piy);
        const float dz = __fsub_rn(pjz, piz);
        const float d2 = __fadd_rn(__fadd_rn(__fmul_rn(dx, dx), __fmul_rn(dy, dy)),
                                   __fmul_rn(dz, dz));
        const float d  = __fsqrt_rn(d2);
        const bool  in = (d <= 5.0f);

        vi[u] = (float)(base + i);       // exact: < 2^24
        vj[u] = (float)(base + j);
        vd[u] = in ? d : 0.0f;
        rr[3*u+0] = in ? dx : 0.0f;
        rr[3*u+1] = in ? dy : 0.0f;
        rr[3*u+2] = in ? dz : 0.0f;

        if (u < 3) {                     // advance (i,t) within the molecule
            ++t;
            if (t == 63) { t = 0; ++i; pix = mp[i*3+0]; piy = mp[i*3+1]; piz = mp[i*3+2]; }
        }
    }

    // layout: [i row | j row | d_ij | r_ij], all float32, all stores 16B-aligned
    *reinterpret_cast<f32x4*>(out + k0)            = vi;
    *reinterpret_cast<f32x4*>(out + NPAIRS + k0)   = vj;
    *reinterpret_cast<f32x4*>(out + 2*NPAIRS + k0) = vd;
    float* rb = out + (long)3 * NPAIRS + (long)3 * k0;   // 3*k0 % 4 == 0
    *reinterpret_cast<f32x4*>(rb + 0) = f32x4{rr[0], rr[1], rr[2],  rr[3]};
    *reinterpret_cast<f32x4*>(rb + 4) = f32x4{rr[4], rr[5], rr[6],  rr[7]};
    *reinterpret_cast<f32x4*>(rb + 8) = f32x4{rr[8], rr[9], rr[10], rr[11]};
}

extern "C" void kernel_launch(void* const* d_in, const int* in_sizes, int n_in,
                              void* d_out, int out_size, void* d_ws, size_t ws_size,
                              hipStream_t stream) {
    const float* pos = (const float*)d_in[0];
    float* out = (float*)d_out;
    const int blocks = (NGROUPS + 255) / 256;   // 7875
    nl_pairs_kernel<<<blocks, 256, 0, stream>>>(pos, out);
}